// Round 1
// baseline (2361.606 us; speedup 1.0000x reference)
//
#include <hip/hip_runtime.h>
#include <stdint.h>

// ---------- exact-rounding helpers (block FMA contraction; match numpy op order) ----------
__device__ inline float mul_rn(float a, float b){ float r; asm("v_mul_f32 %0, %1, %2" : "=v"(r) : "v"(a), "v"(b)); return r; }
__device__ inline float add_rn(float a, float b){ float r; asm("v_add_f32 %0, %1, %2" : "=v"(r) : "v"(a), "v"(b)); return r; }
__device__ inline float sub_rn(float a, float b){ float r; asm("v_sub_f32 %0, %1, %2" : "=v"(r) : "v"(a), "v"(b)); return r; }

typedef uint16_t u16x8 __attribute__((ext_vector_type(8)));

__device__ inline float bf2f(uint16_t u){ return __uint_as_float(((uint32_t)u) << 16); }
__device__ inline uint16_t f2bf(float f){
    uint32_t u = __float_as_uint(f);
    u += 0x7fffu + ((u >> 16) & 1u);   // RNE
    return (uint16_t)(u >> 16);
}

#define NPTS   8192
#define NBATCH 16
#define NPOINT 1024
#define NSAMP  32
#define LCOLS  32768          // NPOINT*NSAMP
#define NTOT   524288.0f      // 16*32768

// ---------- workspace layout (bytes) ----------
#define OFF_FPS   0u               // 16*1024*4            = 65536
#define OFF_GIDX  65536u           // 16*1024*32*4         = 2097152
#define OFF_SUMS  2162688u         // 3 * 1024  (sum[128], ss[128] per layer)
#define OFF_PAR   2165760u         // 3 * 1024  (a[128], c[128] per layer)
#define OFF_WT    2168832u         // 4288+4096+8192 floats = 66304
#define OFF_A     4194304u         // feat  bf16: 67*32768*16*2 = 70254592 ; later t2 (128ch) = 134217728 (fits A+B)
#define OFF_B     74448896u        // t0 bf16: 64*32768*16*2 = 67108864
#define OFF_C     141557760u       // t1 bf16: 67108864 ; ptsT bf16 (16777216) overlaps here early

// ---------- 1) weight transpose: wt[c][o] for contiguous scalar loads ----------
__global__ __launch_bounds__(256) void prep_kernel(const float* __restrict__ w0, const float* __restrict__ w1,
                                                   const float* __restrict__ w2, float* __restrict__ wt0,
                                                   float* __restrict__ wt1, float* __restrict__ wt2){
    int t = blockIdx.x * 256 + threadIdx.x;
    if (t < 64*67){ int o = t / 67, c = t % 67; wt0[c*64 + o] = w0[t]; }
    if (t < 64*64){ int o = t >> 6, c = t & 63; wt1[c*64 + o] = w1[t]; }
    if (t < 128*64){ int o = t >> 6, c = t & 63; wt2[c*128 + o] = w2[t]; }
}

// ---------- 2) FPS: one WG per batch, exact numpy arithmetic, first-index argmax ----------
__global__ __launch_bounds__(256) void fps_kernel(const float* __restrict__ xyz,
                                                  int* __restrict__ fps_idx, float* __restrict__ out_xyz){
    __shared__ float sx[NPTS], sy[NPTS], sz[NPTS];
    __shared__ float rv[4]; __shared__ int ri[4];
    const int b = blockIdx.x, tid = threadIdx.x;
    const float* px = xyz + (size_t)b * 3 * NPTS;
    for (int i = tid; i < NPTS; i += 256){ sx[i] = px[i]; sy[i] = px[NPTS+i]; sz[i] = px[2*NPTS+i]; }
    __syncthreads();
    float X[32], Y[32], Z[32], M[32];
#pragma unroll
    for (int j = 0; j < 32; j++){ int p = tid + j*256; X[j]=sx[p]; Y[j]=sy[p]; Z[j]=sz[p]; M[j]=1e10f; }
    int cur = 0;
    int* fout = fps_idx + b * NPOINT;
    float* oxp = out_xyz + b * 3 * NPOINT;
    for (int t = 0; t < NPOINT; t++){
        if (tid == 0){ fout[t] = cur; oxp[t] = sx[cur]; oxp[NPOINT+t] = sy[cur]; oxp[2*NPOINT+t] = sz[cur]; }
        float cx = sx[cur], cy = sy[cur], cz = sz[cur];
        float bv = -1.0f; int bi = 0;
#pragma unroll
        for (int j = 0; j < 32; j++){
            float dx = sub_rn(X[j], cx), dy = sub_rn(Y[j], cy), dz = sub_rn(Z[j], cz);
            float d  = add_rn(add_rn(mul_rn(dx,dx), mul_rn(dy,dy)), mul_rn(dz,dz));
            float m  = fminf(M[j], d); M[j] = m;
            if (m > bv){ bv = m; bi = tid + j*256; }      // ascending idx within thread -> first max kept
        }
        for (int off = 1; off < 64; off <<= 1){
            float ov = __shfl_xor(bv, off); int oi = __shfl_xor(bi, off);
            if (ov > bv || (ov == bv && oi < bi)){ bv = ov; bi = oi; }
        }
        if ((tid & 63) == 0){ rv[tid>>6] = bv; ri[tid>>6] = bi; }
        __syncthreads();
        bv = rv[0]; bi = ri[0];
#pragma unroll
        for (int w = 1; w < 4; w++){ float ov = rv[w]; int oi = ri[w]; if (ov > bv || (ov == bv && oi < bi)){ bv = ov; bi = oi; } }
        cur = bi;
        __syncthreads();
    }
}

// ---------- 3) points transpose (B,64,N)f32 -> (B,N,64)bf16 ----------
__global__ __launch_bounds__(256) void transpose_kernel(const float* __restrict__ pts, uint16_t* __restrict__ ptsT){
    __shared__ float tile[64][65];
    const int b = blockIdx.x >> 7, n0 = (blockIdx.x & 127) << 6;
    const int tn = threadIdx.x & 63, tg = threadIdx.x >> 6;
    const float* src = pts + (size_t)b * 64 * NPTS + n0;
#pragma unroll
    for (int i = 0; i < 16; i++){ int c = tg*16 + i; tile[c][tn] = src[(size_t)c * NPTS + tn]; }
    __syncthreads();
    uint16_t* dst = ptsT + ((size_t)b * NPTS + n0) * 64;
#pragma unroll
    for (int i = 0; i < 16; i++){ int n = tg*16 + i; dst[(size_t)n * 64 + tn] = f2bf(tile[tn][n]); }
}

// ---------- 4) ball query: one wave per (b,s); first 32 in-radius indices, pad with first ----------
__global__ __launch_bounds__(256) void ballquery_kernel(const float* __restrict__ xyz,
                                                        const int* __restrict__ fps_idx, int* __restrict__ gidx){
    const int w = (blockIdx.x << 2) + (threadIdx.x >> 6);
    const int lane = threadIdx.x & 63;
    const int b = w >> 10, s = w & 1023;
    const float* px = xyz + (size_t)b * 3 * NPTS;
    const int ci = fps_idx[b * NPOINT + s];
    const float cx = px[ci], cy = px[NPTS+ci], cz = px[2*NPTS+ci];
    int* gout = gidx + (size_t)b * LCOLS + s * NSAMP;
    int have = 0, first_p = 0; bool got = false;
    for (int c0 = 0; c0 < NPTS; c0 += 64){
        int p = c0 + lane;
        float dx = sub_rn(px[p], cx), dy = sub_rn(px[NPTS+p], cy), dz = sub_rn(px[2*NPTS+p], cz);
        float d2 = add_rn(add_rn(mul_rn(dx,dx), mul_rn(dy,dy)), mul_rn(dz,dz));
        bool in = (d2 <= 0.01f);
        unsigned long long m = __ballot(in);
        if (m && !got){ first_p = c0 + __ffsll(m) - 1; got = true; }
        if (in){
            int pos = have + __popcll(m & ((1ull << lane) - 1ull));
            if (pos < NSAMP) gout[pos] = p;
        }
        have += __popcll(m);
        if (have >= NSAMP) break;
    }
    for (int pos = have + lane; pos < NSAMP; pos += 64) gout[pos] = first_p;
}

// ---------- 5) build feat (B,67,L) bf16: [xyz[g]-center ; points[g]] ----------
__global__ __launch_bounds__(256) void feat_kernel(const float* __restrict__ xyz, const float* __restrict__ newxyz,
                                                   const uint16_t* __restrict__ ptsT, const int* __restrict__ gidx,
                                                   uint16_t* __restrict__ feat){
    const int l = blockIdx.x * 256 + threadIdx.x;          // 0..524287
    const int b = l >> 15, ls = l & 32767, s = ls >> 5;
    const int g = gidx[(size_t)b * LCOLS + ls];
    const float* px = xyz + (size_t)b * 3 * NPTS;
    const float cx = newxyz[b*3*NPOINT + s], cy = newxyz[b*3*NPOINT + NPOINT + s], cz = newxyz[b*3*NPOINT + 2*NPOINT + s];
    uint16_t* f = feat + (size_t)b * 67 * LCOLS + ls;
    f[0]          = f2bf(sub_rn(px[g], cx));
    f[LCOLS]      = f2bf(sub_rn(px[NPTS+g], cy));
    f[2u*LCOLS]   = f2bf(sub_rn(px[2*NPTS+g], cz));
    const uint16_t* pr = ptsT + ((size_t)b * NPTS + g) * 64;
#pragma unroll
    for (int j = 0; j < 64; j += 8){
        u16x8 v = *(const u16x8*)(pr + j);
#pragma unroll
        for (int e = 0; e < 8; e++) f[(size_t)(3 + j + e) * LCOLS] = v[e];
    }
}

// ---------- 6) matmul: out[o][l] = sum_c W[o][c] * act(in[c][l]) + bias ----------
template<int CIN, int COUT, bool ACT>
__global__ __launch_bounds__(256) void mm_kernel(const uint16_t* __restrict__ xin, const float* __restrict__ wt,
                                                 const float* __restrict__ bias, const float* __restrict__ ac,
                                                 uint16_t* __restrict__ xout){
    const int b = blockIdx.x >> 7;
    const int l = ((blockIdx.x & 127) << 8) + threadIdx.x;
    const uint16_t* xp = xin + (size_t)b * CIN * LCOLS + l;
    float f[CIN];
#pragma unroll
    for (int c = 0; c < CIN; c++){
        float v = bf2f(xp[(size_t)c * LCOLS]);
        if (ACT) v = fmaxf(fmaf(ac[c], v, ac[128 + c]), 0.0f);
        f[c] = v;
    }
    uint16_t* op = xout + (size_t)b * COUT * LCOLS + l;
    for (int o0 = 0; o0 < COUT; o0 += 8){
        float acc[8];
#pragma unroll
        for (int j = 0; j < 8; j++) acc[j] = bias[o0 + j];
#pragma unroll
        for (int c = 0; c < CIN; c++){
            const float* wr = wt + c * COUT + o0;
#pragma unroll
            for (int j = 0; j < 8; j++) acc[j] = fmaf(wr[j], f[c], acc[j]);
        }
#pragma unroll
        for (int j = 0; j < 8; j++) op[(size_t)(o0 + j) * LCOLS] = f2bf(acc[j]);
    }
}

// ---------- 7) per-channel sum / sumsq ----------
template<int C>
__global__ __launch_bounds__(256) void stats_kernel(const uint16_t* __restrict__ x, float* __restrict__ sums){
    const int bid = blockIdx.x;
    const int tile = bid & 3, rest = bid >> 2;
    const int o = rest % C, b = rest / C;
    const uint16_t* p = x + (size_t)(b * C + o) * LCOLS + tile * 8192;
    float s = 0.f, ss = 0.f;
#pragma unroll
    for (int j = 0; j < 4; j++){
        u16x8 v = *(const u16x8*)(p + threadIdx.x * 8 + j * 2048);
#pragma unroll
        for (int e = 0; e < 8; e++){ float f = bf2f(v[e]); s += f; ss = fmaf(f, f, ss); }
    }
    for (int off = 1; off < 64; off <<= 1){ s += __shfl_xor(s, off); ss += __shfl_xor(ss, off); }
    __shared__ float ls[4], lss[4];
    if ((threadIdx.x & 63) == 0){ ls[threadIdx.x>>6] = s; lss[threadIdx.x>>6] = ss; }
    __syncthreads();
    if (threadIdx.x == 0){
        atomicAdd(&sums[o],       ls[0]+ls[1]+ls[2]+ls[3]);
        atomicAdd(&sums[128 + o], lss[0]+lss[1]+lss[2]+lss[3]);
    }
}

// ---------- 8) BN params -> per-channel affine a,c ----------
__global__ void params_kernel(const float* __restrict__ sums, const float* __restrict__ g,
                              const float* __restrict__ beta, float* __restrict__ ac, int C){
    int o = threadIdx.x;
    if (o < C){
        const float inv = 1.0f / NTOT;
        float mean = sums[o] * inv;
        float var  = sums[128 + o] * inv - mean * mean;
        float a = g[o] / sqrtf(var + 1e-5f);
        ac[o] = a;
        ac[128 + o] = fmaf(-mean, a, beta[o]);
    }
}

// ---------- 9) final: relu(a*x+c), global max over all 32768 columns ----------
__global__ __launch_bounds__(256) void pool_kernel(const uint16_t* __restrict__ x, const float* __restrict__ ac,
                                                   float* __restrict__ out){
    const int bo = blockIdx.x;                  // b*128 + o
    const int o = bo & 127;
    const uint16_t* p = x + (size_t)bo * LCOLS;
    const float a = ac[o], cc = ac[128 + o];
    float m = 0.0f;                             // relu output >= 0
    for (int i = threadIdx.x * 8; i < LCOLS; i += 2048){
        u16x8 v = *(const u16x8*)(p + i);
#pragma unroll
        for (int e = 0; e < 8; e++){ float f = bf2f(v[e]); m = fmaxf(m, fmaxf(fmaf(a, f, cc), 0.0f)); }
    }
    for (int off = 1; off < 64; off <<= 1) m = fmaxf(m, __shfl_xor(m, off));
    __shared__ float sm[4];
    if ((threadIdx.x & 63) == 0) sm[threadIdx.x>>6] = m;
    __syncthreads();
    if (threadIdx.x == 0) out[bo] = fmaxf(fmaxf(sm[0], sm[1]), fmaxf(sm[2], sm[3]));
}

extern "C" void kernel_launch(void* const* d_in, const int* in_sizes, int n_in,
                              void* d_out, int out_size, void* d_ws, size_t ws_size,
                              hipStream_t stream){
    const float* xyz = (const float*)d_in[0];
    const float* pts = (const float*)d_in[1];
    const float* w0  = (const float*)d_in[2];  const float* b0  = (const float*)d_in[3];
    const float* g0  = (const float*)d_in[4];  const float* be0 = (const float*)d_in[5];
    const float* w1  = (const float*)d_in[6];  const float* b1  = (const float*)d_in[7];
    const float* g1  = (const float*)d_in[8];  const float* be1 = (const float*)d_in[9];
    const float* w2  = (const float*)d_in[10]; const float* b2  = (const float*)d_in[11];
    const float* g2  = (const float*)d_in[12]; const float* be2 = (const float*)d_in[13];
    float* out = (float*)d_out;
    char* ws = (char*)d_ws;

    int*   fps_idx = (int*)(ws + OFF_FPS);
    int*   gidx    = (int*)(ws + OFF_GIDX);
    float* sums    = (float*)(ws + OFF_SUMS);   // 3 regions of 256 floats
    float* par     = (float*)(ws + OFF_PAR);    // 3 regions of 256 floats
    float* wt0     = (float*)(ws + OFF_WT);
    float* wt1     = wt0 + 67*64;
    float* wt2     = wt1 + 64*64;
    uint16_t* feat = (uint16_t*)(ws + OFF_A);
    uint16_t* t0   = (uint16_t*)(ws + OFF_B);
    uint16_t* t1   = (uint16_t*)(ws + OFF_C);
    uint16_t* ptsT = (uint16_t*)(ws + OFF_C);   // dead before t1 is written
    uint16_t* t2   = (uint16_t*)(ws + OFF_A);   // feat+t0 dead before t2 is written

    hipMemsetAsync(ws + OFF_SUMS, 0, 3072, stream);
    prep_kernel<<<32, 256, 0, stream>>>(w0, w1, w2, wt0, wt1, wt2);
    fps_kernel<<<NBATCH, 256, 0, stream>>>(xyz, fps_idx, out);
    transpose_kernel<<<2048, 256, 0, stream>>>(pts, ptsT);
    ballquery_kernel<<<4096, 256, 0, stream>>>(xyz, fps_idx, gidx);
    feat_kernel<<<2048, 256, 0, stream>>>(xyz, out, ptsT, gidx, feat);

    mm_kernel<67, 64, false><<<2048, 256, 0, stream>>>(feat, wt0, b0, par, t0);
    stats_kernel<64><<<16*64*4, 256, 0, stream>>>(t0, sums);
    params_kernel<<<1, 128, 0, stream>>>(sums, g0, be0, par, 64);

    mm_kernel<64, 64, true><<<2048, 256, 0, stream>>>(t0, wt1, b1, par, t1);
    stats_kernel<64><<<16*64*4, 256, 0, stream>>>(t1, sums + 256);
    params_kernel<<<1, 128, 0, stream>>>(sums + 256, g1, be1, par + 256, 64);

    mm_kernel<64, 128, true><<<2048, 256, 0, stream>>>(t1, wt2, b2, par + 256, t2);
    stats_kernel<128><<<16*128*4, 256, 0, stream>>>(t2, sums + 512);
    params_kernel<<<1, 128, 0, stream>>>(sums + 512, g2, be2, par + 512, 128);

    pool_kernel<<<2048, 256, 0, stream>>>(t2, par + 512, out + 49152);
}

// Round 2
// 1930.330 us; speedup vs baseline: 1.2234x; 1.2234x over previous
//
#include <hip/hip_runtime.h>
#include <stdint.h>
#include <limits.h>

// ---------- exact-rounding helpers (block FMA contraction; match numpy op order) ----------
__device__ inline float mul_rn(float a, float b){ float r; asm("v_mul_f32 %0, %1, %2" : "=v"(r) : "v"(a), "v"(b)); return r; }
__device__ inline float add_rn(float a, float b){ float r; asm("v_add_f32 %0, %1, %2" : "=v"(r) : "v"(a), "v"(b)); return r; }
__device__ inline float sub_rn(float a, float b){ float r; asm("v_sub_f32 %0, %1, %2" : "=v"(r) : "v"(a), "v"(b)); return r; }

typedef uint16_t u16x8 __attribute__((ext_vector_type(8)));

__device__ inline float bf2f(uint16_t u){ return __uint_as_float(((uint32_t)u) << 16); }
__device__ inline uint16_t f2bf(float f){
    uint32_t u = __float_as_uint(f);
    u += 0x7fffu + ((u >> 16) & 1u);   // RNE
    return (uint16_t)(u >> 16);
}

#define NPTS   8192
#define NBATCH 16
#define NPOINT 1024
#define NSAMP  32
#define LCOLS  32768          // NPOINT*NSAMP
#define NTOT   524288.0f      // 16*32768

// ---------- workspace layout (bytes) ----------
#define OFF_FPS   0u               // 16*1024*4            = 65536
#define OFF_GIDX  65536u           // 16*1024*32*4         = 2097152
#define OFF_SUMS  2162688u         // 3 * 1024  (sum[128], ss[128] per layer)
#define OFF_PAR   2165760u         // 3 * 1024  (a[128], c[128] per layer)
#define OFF_WT    2168832u         // 4288+4096+8192 floats = 66304
#define OFF_A     4194304u         // feat  bf16: 67*32768*16*2 = 70254592 ; later t2 (128ch)
#define OFF_B     74448896u        // t0 bf16: 64*32768*16*2 = 67108864
#define OFF_C     141557760u       // t1 bf16: 67108864 ; ptsT bf16 (16777216) overlaps here early

// ---------- 1) weight transpose: wt[c][o] for contiguous loads ----------
__global__ __launch_bounds__(256) void prep_kernel(const float* __restrict__ w0, const float* __restrict__ w1,
                                                   const float* __restrict__ w2, float* __restrict__ wt0,
                                                   float* __restrict__ wt1, float* __restrict__ wt2){
    int t = blockIdx.x * 256 + threadIdx.x;
    if (t < 64*67){ int o = t / 67, c = t % 67; wt0[c*64 + o] = w0[t]; }
    if (t < 64*64){ int o = t >> 6, c = t & 63; wt1[c*64 + o] = w1[t]; }
    if (t < 128*64){ int o = t >> 6, c = t & 63; wt2[c*128 + o] = w2[t]; }
}

// ---------- 2) FPS: one WG (1024 thr) per batch; value-only reduce + index recovery ----------
__global__ __launch_bounds__(1024) void fps_kernel(const float* __restrict__ xyz,
                                                   int* __restrict__ fps_idx, float* __restrict__ out_xyz){
    __shared__ float sx[NPTS], sy[NPTS], sz[NPTS];
    __shared__ __align__(16) float rv[16];
    __shared__ int rcur[2];
    const int b = blockIdx.x, tid = threadIdx.x;
    const int lane = tid & 63, wid = tid >> 6;
    const float* px = xyz + (size_t)b * 3 * NPTS;
    for (int i = tid; i < NPTS; i += 1024){ sx[i] = px[i]; sy[i] = px[NPTS+i]; sz[i] = px[2*NPTS+i]; }
    if (tid < 2) rcur[tid] = INT_MAX;
    __syncthreads();
    float X[8], Y[8], Z[8], M[8];
#pragma unroll
    for (int j = 0; j < 8; j++){ int p = tid + (j << 10); X[j]=sx[p]; Y[j]=sy[p]; Z[j]=sz[p]; M[j]=1e10f; }
    int cur = 0;
    int* fout = fps_idx + b * NPOINT;
    float* oxp = out_xyz + b * 3 * NPOINT;
    for (int t = 0; t < NPOINT; t++){
        const int pt = t & 1;
        if (tid == 0){ fout[t] = cur; oxp[t] = sx[cur]; oxp[NPOINT+t] = sy[cur]; oxp[2*NPOINT+t] = sz[cur]; }
        const float cx = sx[cur], cy = sy[cur], cz = sz[cur];
#pragma unroll
        for (int j = 0; j < 8; j++){
            float dx = sub_rn(X[j], cx), dy = sub_rn(Y[j], cy), dz = sub_rn(Z[j], cz);
            float d  = add_rn(add_rn(mul_rn(dx,dx), mul_rn(dy,dy)), mul_rn(dz,dz));
            M[j] = fminf(M[j], d);
        }
        // thread-local max (values only; exact bit propagation through fmax)
        float mt = fmaxf(fmaxf(fmaxf(M[0],M[1]), fmaxf(M[2],M[3])),
                         fmaxf(fmaxf(M[4],M[5]), fmaxf(M[6],M[7])));
        // wave reduce (value only)
        float wv = mt;
#pragma unroll
        for (int off = 1; off < 64; off <<= 1) wv = fmaxf(wv, __shfl_xor(wv, off));
        if (lane == 0) rv[wid] = wv;
        __syncthreads();                                   // barrier 1
        const float4* rv4 = (const float4*)rv;
        float4 r0 = rv4[0], r1 = rv4[1], r2 = rv4[2], r3 = rv4[3];
        float bv = fmaxf(fmaxf(fmaxf(fmaxf(r0.x,r0.y),fmaxf(r0.z,r0.w)),
                               fmaxf(fmaxf(r1.x,r1.y),fmaxf(r1.z,r1.w))),
                         fmaxf(fmaxf(fmaxf(r2.x,r2.y),fmaxf(r2.z,r2.w)),
                               fmaxf(fmaxf(r3.x,r3.y),fmaxf(r3.z,r3.w))));
        if (tid == 0) rcur[pt ^ 1] = INT_MAX;              // reset other buffer inside barrier window
        if (mt == bv){                                     // rare: only owning thread(s) scan
            int p = INT_MAX;
#pragma unroll
            for (int j = 7; j >= 0; j--) if (M[j] == bv) p = (j << 10) + tid;  // descending: smallest j wins
            atomicMin(&rcur[pt], p);                       // smallest point index = numpy first-occurrence
        }
        __syncthreads();                                   // barrier 2
        cur = rcur[pt];
    }
}

// ---------- 3) points transpose (B,64,N)f32 -> (B,N,64)bf16 ----------
__global__ __launch_bounds__(256) void transpose_kernel(const float* __restrict__ pts, uint16_t* __restrict__ ptsT){
    __shared__ float tile[64][65];
    const int b = blockIdx.x >> 7, n0 = (blockIdx.x & 127) << 6;
    const int tn = threadIdx.x & 63, tg = threadIdx.x >> 6;
    const float* src = pts + (size_t)b * 64 * NPTS + n0;
#pragma unroll
    for (int i = 0; i < 16; i++){ int c = tg*16 + i; tile[c][tn] = src[(size_t)c * NPTS + tn]; }
    __syncthreads();
    uint16_t* dst = ptsT + ((size_t)b * NPTS + n0) * 64;
#pragma unroll
    for (int i = 0; i < 16; i++){ int n = tg*16 + i; dst[(size_t)n * 64 + tn] = f2bf(tile[tn][n]); }
}

// ---------- 4) ball query: one wave per (b,s) ----------
__global__ __launch_bounds__(256) void ballquery_kernel(const float* __restrict__ xyz,
                                                        const int* __restrict__ fps_idx, int* __restrict__ gidx){
    const int w = (blockIdx.x << 2) + (threadIdx.x >> 6);
    const int lane = threadIdx.x & 63;
    const int b = w >> 10, s = w & 1023;
    const float* px = xyz + (size_t)b * 3 * NPTS;
    const int ci = fps_idx[b * NPOINT + s];
    const float cx = px[ci], cy = px[NPTS+ci], cz = px[2*NPTS+ci];
    int* gout = gidx + (size_t)b * LCOLS + s * NSAMP;
    int have = 0, first_p = 0; bool got = false;
    for (int c0 = 0; c0 < NPTS; c0 += 64){
        int p = c0 + lane;
        float dx = sub_rn(px[p], cx), dy = sub_rn(px[NPTS+p], cy), dz = sub_rn(px[2*NPTS+p], cz);
        float d2 = add_rn(add_rn(mul_rn(dx,dx), mul_rn(dy,dy)), mul_rn(dz,dz));
        bool in = (d2 <= 0.01f);
        unsigned long long m = __ballot(in);
        if (m && !got){ first_p = c0 + __ffsll(m) - 1; got = true; }
        if (in){
            int pos = have + __popcll(m & ((1ull << lane) - 1ull));
            if (pos < NSAMP) gout[pos] = p;
        }
        have += __popcll(m);
        if (have >= NSAMP) break;
    }
    for (int pos = have + lane; pos < NSAMP; pos += 64) gout[pos] = first_p;
}

// ---------- 5) build feat (B,67,L) bf16: [xyz[g]-center ; points[g]] ----------
__global__ __launch_bounds__(256) void feat_kernel(const float* __restrict__ xyz, const float* __restrict__ newxyz,
                                                   const uint16_t* __restrict__ ptsT, const int* __restrict__ gidx,
                                                   uint16_t* __restrict__ feat){
    const int l = blockIdx.x * 256 + threadIdx.x;          // 0..524287
    const int b = l >> 15, ls = l & 32767, s = ls >> 5;
    const int g = gidx[(size_t)b * LCOLS + ls];
    const float* px = xyz + (size_t)b * 3 * NPTS;
    const float cx = newxyz[b*3*NPOINT + s], cy = newxyz[b*3*NPOINT + NPOINT + s], cz = newxyz[b*3*NPOINT + 2*NPOINT + s];
    uint16_t* f = feat + (size_t)b * 67 * LCOLS + ls;
    f[0]          = f2bf(sub_rn(px[g], cx));
    f[LCOLS]      = f2bf(sub_rn(px[NPTS+g], cy));
    f[2u*LCOLS]   = f2bf(sub_rn(px[2*NPTS+g], cz));
    const uint16_t* pr = ptsT + ((size_t)b * NPTS + g) * 64;
#pragma unroll
    for (int j = 0; j < 64; j += 8){
        u16x8 v = *(const u16x8*)(pr + j);
#pragma unroll
        for (int e = 0; e < 8; e++) f[(size_t)(3 + j + e) * LCOLS] = v[e];
    }
}

// ---------- 6) matmul: out[o][l] = sum_c W[o][c] * act(in[c][l]) + bias ; W in LDS ----------
template<int CIN, int COUT, bool ACT>
__global__ __launch_bounds__(256) void mm_kernel(const uint16_t* __restrict__ xin, const float* __restrict__ wt,
                                                 const float* __restrict__ bias, const float* __restrict__ ac,
                                                 uint16_t* __restrict__ xout){
    __shared__ __align__(16) float sw[CIN * COUT];
    __shared__ float sb[COUT];
    __shared__ float sa[2 * CIN];
    for (int i = threadIdx.x; i < CIN * COUT; i += 256) sw[i] = wt[i];
    if (threadIdx.x < COUT) sb[threadIdx.x] = bias[threadIdx.x];
    if (ACT && threadIdx.x < CIN){ sa[threadIdx.x] = ac[threadIdx.x]; sa[CIN + threadIdx.x] = ac[128 + threadIdx.x]; }
    __syncthreads();
    const int b = blockIdx.x >> 7;
    const int l = ((blockIdx.x & 127) << 8) + threadIdx.x;
    const uint16_t* xp = xin + (size_t)b * CIN * LCOLS + l;
    float f[CIN];
#pragma unroll
    for (int c = 0; c < CIN; c++){
        float v = bf2f(xp[(size_t)c * LCOLS]);
        if (ACT) v = fmaxf(fmaf(sa[c], v, sa[CIN + c]), 0.0f);
        f[c] = v;
    }
    uint16_t* op = xout + (size_t)b * COUT * LCOLS + l;
#pragma unroll
    for (int o0 = 0; o0 < COUT; o0 += 16){
        float acc[16];
#pragma unroll
        for (int j = 0; j < 16; j++) acc[j] = sb[o0 + j];
#pragma unroll
        for (int c = 0; c < CIN; c++){
            const float4* wr = (const float4*)(sw + c * COUT + o0);  // uniform -> LDS broadcast
            float4 w0_ = wr[0], w1_ = wr[1], w2_ = wr[2], w3_ = wr[3];
            const float fc = f[c];
            acc[0]  = fmaf(w0_.x, fc, acc[0]);  acc[1]  = fmaf(w0_.y, fc, acc[1]);
            acc[2]  = fmaf(w0_.z, fc, acc[2]);  acc[3]  = fmaf(w0_.w, fc, acc[3]);
            acc[4]  = fmaf(w1_.x, fc, acc[4]);  acc[5]  = fmaf(w1_.y, fc, acc[5]);
            acc[6]  = fmaf(w1_.z, fc, acc[6]);  acc[7]  = fmaf(w1_.w, fc, acc[7]);
            acc[8]  = fmaf(w2_.x, fc, acc[8]);  acc[9]  = fmaf(w2_.y, fc, acc[9]);
            acc[10] = fmaf(w2_.z, fc, acc[10]); acc[11] = fmaf(w2_.w, fc, acc[11]);
            acc[12] = fmaf(w3_.x, fc, acc[12]); acc[13] = fmaf(w3_.y, fc, acc[13]);
            acc[14] = fmaf(w3_.z, fc, acc[14]); acc[15] = fmaf(w3_.w, fc, acc[15]);
        }
#pragma unroll
        for (int j = 0; j < 16; j++) op[(size_t)(o0 + j) * LCOLS] = f2bf(acc[j]);
    }
}

// ---------- 7) per-channel sum / sumsq ----------
template<int C>
__global__ __launch_bounds__(256) void stats_kernel(const uint16_t* __restrict__ x, float* __restrict__ sums){
    const int bid = blockIdx.x;
    const int tile = bid & 3, rest = bid >> 2;
    const int o = rest % C, b = rest / C;
    const uint16_t* p = x + (size_t)(b * C + o) * LCOLS + tile * 8192;
    float s = 0.f, ss = 0.f;
#pragma unroll
    for (int j = 0; j < 4; j++){
        u16x8 v = *(const u16x8*)(p + threadIdx.x * 8 + j * 2048);
#pragma unroll
        for (int e = 0; e < 8; e++){ float f = bf2f(v[e]); s += f; ss = fmaf(f, f, ss); }
    }
    for (int off = 1; off < 64; off <<= 1){ s += __shfl_xor(s, off); ss += __shfl_xor(ss, off); }
    __shared__ float ls[4], lss[4];
    if ((threadIdx.x & 63) == 0){ ls[threadIdx.x>>6] = s; lss[threadIdx.x>>6] = ss; }
    __syncthreads();
    if (threadIdx.x == 0){
        atomicAdd(&sums[o],       ls[0]+ls[1]+ls[2]+ls[3]);
        atomicAdd(&sums[128 + o], lss[0]+lss[1]+lss[2]+lss[3]);
    }
}

// ---------- 8) BN params -> per-channel affine a,c ----------
__global__ void params_kernel(const float* __restrict__ sums, const float* __restrict__ g,
                              const float* __restrict__ beta, float* __restrict__ ac, int C){
    int o = threadIdx.x;
    if (o < C){
        const float inv = 1.0f / NTOT;
        float mean = sums[o] * inv;
        float var  = sums[128 + o] * inv - mean * mean;
        float a = g[o] / sqrtf(var + 1e-5f);
        ac[o] = a;
        ac[128 + o] = fmaf(-mean, a, beta[o]);
    }
}

// ---------- 9) final: relu(a*x+c), global max over all 32768 columns ----------
__global__ __launch_bounds__(256) void pool_kernel(const uint16_t* __restrict__ x, const float* __restrict__ ac,
                                                   float* __restrict__ out){
    const int bo = blockIdx.x;                  // b*128 + o
    const int o = bo & 127;
    const uint16_t* p = x + (size_t)bo * LCOLS;
    const float a = ac[o], cc = ac[128 + o];
    float m = 0.0f;                             // relu output >= 0
    for (int i = threadIdx.x * 8; i < LCOLS; i += 2048){
        u16x8 v = *(const u16x8*)(p + i);
#pragma unroll
        for (int e = 0; e < 8; e++){ float f = bf2f(v[e]); m = fmaxf(m, fmaxf(fmaf(a, f, cc), 0.0f)); }
    }
    for (int off = 1; off < 64; off <<= 1) m = fmaxf(m, __shfl_xor(m, off));
    __shared__ float sm[4];
    if ((threadIdx.x & 63) == 0) sm[threadIdx.x>>6] = m;
    __syncthreads();
    if (threadIdx.x == 0) out[bo] = fmaxf(fmaxf(sm[0], sm[1]), fmaxf(sm[2], sm[3]));
}

extern "C" void kernel_launch(void* const* d_in, const int* in_sizes, int n_in,
                              void* d_out, int out_size, void* d_ws, size_t ws_size,
                              hipStream_t stream){
    const float* xyz = (const float*)d_in[0];
    const float* pts = (const float*)d_in[1];
    const float* w0  = (const float*)d_in[2];  const float* b0  = (const float*)d_in[3];
    const float* g0  = (const float*)d_in[4];  const float* be0 = (const float*)d_in[5];
    const float* w1  = (const float*)d_in[6];  const float* b1  = (const float*)d_in[7];
    const float* g1  = (const float*)d_in[8];  const float* be1 = (const float*)d_in[9];
    const float* w2  = (const float*)d_in[10]; const float* b2  = (const float*)d_in[11];
    const float* g2  = (const float*)d_in[12]; const float* be2 = (const float*)d_in[13];
    float* out = (float*)d_out;
    char* ws = (char*)d_ws;

    int*   fps_idx = (int*)(ws + OFF_FPS);
    int*   gidx    = (int*)(ws + OFF_GIDX);
    float* sums    = (float*)(ws + OFF_SUMS);   // 3 regions of 256 floats
    float* par     = (float*)(ws + OFF_PAR);    // 3 regions of 256 floats
    float* wt0     = (float*)(ws + OFF_WT);
    float* wt1     = wt0 + 67*64;
    float* wt2     = wt1 + 64*64;
    uint16_t* feat = (uint16_t*)(ws + OFF_A);
    uint16_t* t0   = (uint16_t*)(ws + OFF_B);
    uint16_t* t1   = (uint16_t*)(ws + OFF_C);
    uint16_t* ptsT = (uint16_t*)(ws + OFF_C);   // dead before t1 is written
    uint16_t* t2   = (uint16_t*)(ws + OFF_A);   // feat+t0 dead before t2 is written

    hipMemsetAsync(ws + OFF_SUMS, 0, 3072, stream);
    prep_kernel<<<32, 256, 0, stream>>>(w0, w1, w2, wt0, wt1, wt2);
    fps_kernel<<<NBATCH, 1024, 0, stream>>>(xyz, fps_idx, out);
    transpose_kernel<<<2048, 256, 0, stream>>>(pts, ptsT);
    ballquery_kernel<<<4096, 256, 0, stream>>>(xyz, fps_idx, gidx);
    feat_kernel<<<2048, 256, 0, stream>>>(xyz, out, ptsT, gidx, feat);

    mm_kernel<67, 64, false><<<2048, 256, 0, stream>>>(feat, wt0, b0, par, t0);
    stats_kernel<64><<<16*64*4, 256, 0, stream>>>(t0, sums);
    params_kernel<<<1, 128, 0, stream>>>(sums, g0, be0, par, 64);

    mm_kernel<64, 64, true><<<2048, 256, 0, stream>>>(t0, wt1, b1, par, t1);
    stats_kernel<64><<<16*64*4, 256, 0, stream>>>(t1, sums + 256);
    params_kernel<<<1, 128, 0, stream>>>(sums + 256, g1, be1, par + 256, 64);

    mm_kernel<64, 128, true><<<2048, 256, 0, stream>>>(t1, wt2, b2, par + 256, t2);
    stats_kernel<128><<<16*128*4, 256, 0, stream>>>(t2, sums + 512);
    params_kernel<<<1, 128, 0, stream>>>(sums + 512, g2, be2, par + 512, 128);

    pool_kernel<<<2048, 256, 0, stream>>>(t2, par + 512, out + 49152);
}

// Round 3
// 1623.186 us; speedup vs baseline: 1.4549x; 1.1892x over previous
//
#include <hip/hip_runtime.h>
#include <stdint.h>
#include <limits.h>

// ---------- exact-rounding helpers (block FMA contraction; match numpy op order) ----------
__device__ inline float mul_rn(float a, float b){ float r; asm("v_mul_f32 %0, %1, %2" : "=v"(r) : "v"(a), "v"(b)); return r; }
__device__ inline float add_rn(float a, float b){ float r; asm("v_add_f32 %0, %1, %2" : "=v"(r) : "v"(a), "v"(b)); return r; }
__device__ inline float sub_rn(float a, float b){ float r; asm("v_sub_f32 %0, %1, %2" : "=v"(r) : "v"(a), "v"(b)); return r; }

typedef uint16_t u16x8 __attribute__((ext_vector_type(8)));

__device__ inline float bf2f(uint16_t u){ return __uint_as_float(((uint32_t)u) << 16); }
__device__ inline uint16_t f2bf(float f){
    uint32_t u = __float_as_uint(f);
    u += 0x7fffu + ((u >> 16) & 1u);   // RNE
    return (uint16_t)(u >> 16);
}
// monotonic uint key for float (total order): k(f) increasing in f
__device__ inline unsigned fkey(float f){
    unsigned u = __float_as_uint(f);
    return (u & 0x80000000u) ? ~u : (u | 0x80000000u);
}
__device__ inline float funkey(unsigned k){
    unsigned u = (k & 0x80000000u) ? (k ^ 0x80000000u) : ~k;
    return __uint_as_float(u);
}

#define NPTS   8192
#define NBATCH 16
#define NPOINT 1024
#define NSAMP  32
#define LCOLS  32768          // NPOINT*NSAMP
#define NTOT   524288.0f      // 16*32768
#define NBUCK  32

// ---------- workspace layout (bytes) ----------
#define OFF_FPS   0u               // 16*1024*4 = 65536
#define OFF_GIDX  65536u           // 16*1024*32*4 = 2097152
#define OFF_SSC   2162688u         // 3 layers * 32 buckets * 256 f32 = 98304
#define OFF_PAR   2260992u         // 2 layers * 256 f32 = 2048
#define OFF_MM    2263040u         // mmax 2048 u32 ; mmin 2048 u32 = 16384
#define OFF_WT    2279424u         // 66304
#define OFF_T0    4194304u         // 67108864
#define OFF_T1    71303168u        // 67108864
#define OFF_PTST  138412032u       // 16777216 (end 155189248)

// ---------- 1) weight transpose: wt[c][o] ----------
__global__ __launch_bounds__(256) void prep_kernel(const float* __restrict__ w0, const float* __restrict__ w1,
                                                   const float* __restrict__ w2, float* __restrict__ wt0,
                                                   float* __restrict__ wt1, float* __restrict__ wt2){
    int t = blockIdx.x * 256 + threadIdx.x;
    if (t < 64*67){ int o = t / 67, c = t % 67; wt0[c*64 + o] = w0[t]; }
    if (t < 64*64){ int o = t >> 6, c = t & 63; wt1[c*64 + o] = w1[t]; }
    if (t < 128*64){ int o = t >> 6, c = t & 63; wt2[c*128 + o] = w2[t]; }
}

// ---------- 2) FPS: one WG (1024 thr) per batch; ONE barrier/iter via packed u64 LDS atomicMax ----------
__global__ __launch_bounds__(1024) void fps_kernel(const float* __restrict__ xyz,
                                                   int* __restrict__ fps_idx, float* __restrict__ out_xyz){
    __shared__ float sx[NPTS], sy[NPTS], sz[NPTS];
    __shared__ unsigned long long slot[3];    // rotating: used t, reset t+1, safe gap t+2
    const int b = blockIdx.x, tid = threadIdx.x;
    const float* px = xyz + (size_t)b * 3 * NPTS;
    for (int i = tid; i < NPTS; i += 1024){ sx[i] = px[i]; sy[i] = px[NPTS+i]; sz[i] = px[2*NPTS+i]; }
    if (tid < 3) slot[tid] = 0ull;
    __syncthreads();
    float X[8], Y[8], Z[8], M[8];
#pragma unroll
    for (int j = 0; j < 8; j++){ int p = tid + (j << 10); X[j]=sx[p]; Y[j]=sy[p]; Z[j]=sz[p]; M[j]=1e10f; }
    int cur = 0, r = 0;
    int* fout = fps_idx + b * NPOINT;
    float* oxp = out_xyz + b * 3 * NPOINT;
    for (int t = 0; t < NPOINT; t++){
        if (tid == 0){ fout[t] = cur; oxp[t] = sx[cur]; oxp[NPOINT+t] = sy[cur]; oxp[2*NPOINT+t] = sz[cur]; }
        const float cx = sx[cur], cy = sy[cur], cz = sz[cur];
#pragma unroll
        for (int j = 0; j < 8; j++){
            float dx = sub_rn(X[j], cx), dy = sub_rn(Y[j], cy), dz = sub_rn(Z[j], cz);
            float d  = add_rn(add_rn(mul_rn(dx,dx), mul_rn(dy,dy)), mul_rn(dz,dz));
            M[j] = fminf(M[j], d);
        }
        float mt = fmaxf(fmaxf(fmaxf(M[0],M[1]), fmaxf(M[2],M[3])),
                         fmaxf(fmaxf(M[4],M[5]), fmaxf(M[6],M[7])));
        float wv = mt;
#pragma unroll
        for (int off = 1; off < 64; off <<= 1) wv = fmaxf(wv, __shfl_xor(wv, off));
        if (mt == wv){                                   // candidate lanes only (≥1 per wave)
            int p = INT_MAX;
#pragma unroll
            for (int j = 7; j >= 0; j--) if (M[j] == wv) p = (j << 10) + tid;   // smallest j wins
            unsigned long long key = ((unsigned long long)__float_as_uint(wv) << 32) | (unsigned)(~p);
            atomicMax(&slot[r], key);                    // value primary; ~p -> smallest index wins ties
        }
        int rn = r + 1; if (rn == 3) rn = 0;
        if (tid == 0) slot[rn] = 0ull;                   // last read of slot[rn] was 2 barriers ago: safe
        __syncthreads();
        cur = (int)(~((unsigned)slot[r]));
        r = rn;
    }
}

// ---------- 3) points transpose (B,64,N)f32 -> (B,N,64)bf16 ----------
__global__ __launch_bounds__(256) void transpose_kernel(const float* __restrict__ pts, uint16_t* __restrict__ ptsT){
    __shared__ float tile[64][65];
    const int b = blockIdx.x >> 7, n0 = (blockIdx.x & 127) << 6;
    const int tn = threadIdx.x & 63, tg = threadIdx.x >> 6;
    const float* src = pts + (size_t)b * 64 * NPTS + n0;
#pragma unroll
    for (int i = 0; i < 16; i++){ int c = tg*16 + i; tile[c][tn] = src[(size_t)c * NPTS + tn]; }
    __syncthreads();
    uint16_t* dst = ptsT + ((size_t)b * NPTS + n0) * 64;
#pragma unroll
    for (int i = 0; i < 16; i++){ int n = tg*16 + i; dst[(size_t)n * 64 + tn] = f2bf(tile[tn][n]); }
}

// ---------- 4) ball query: one wave per (b,s) ----------
__global__ __launch_bounds__(256) void ballquery_kernel(const float* __restrict__ xyz,
                                                        const int* __restrict__ fps_idx, int* __restrict__ gidx){
    const int w = (blockIdx.x << 2) + (threadIdx.x >> 6);
    const int lane = threadIdx.x & 63;
    const int b = w >> 10, s = w & 1023;
    const float* px = xyz + (size_t)b * 3 * NPTS;
    const int ci = fps_idx[b * NPOINT + s];
    const float cx = px[ci], cy = px[NPTS+ci], cz = px[2*NPTS+ci];
    int* gout = gidx + (size_t)b * LCOLS + s * NSAMP;
    int have = 0, first_p = 0; bool got = false;
    for (int c0 = 0; c0 < NPTS; c0 += 64){
        int p = c0 + lane;
        float dx = sub_rn(px[p], cx), dy = sub_rn(px[NPTS+p], cy), dz = sub_rn(px[2*NPTS+p], cz);
        float d2 = add_rn(add_rn(mul_rn(dx,dx), mul_rn(dy,dy)), mul_rn(dz,dz));
        bool in = (d2 <= 0.01f);
        unsigned long long m = __ballot(in);
        if (m && !got){ first_p = c0 + __ffsll(m) - 1; got = true; }
        if (in){
            int pos = have + __popcll(m & ((1ull << lane) - 1ull));
            if (pos < NSAMP) gout[pos] = p;
        }
        have += __popcll(m);
        if (have >= NSAMP) break;
    }
    for (int pos = have + lane; pos < NSAMP; pos += 64) gout[pos] = first_p;
}

// ---------- 5) fused conv+BN-stats kernel ----------
// GATHER: build f[] from (xyz, ptsT, gidx) instead of reading xin.
// WRITE:  write bf16 outputs (skipped for last layer).
// MAXMIN: also reduce per-(b,ch) max/min (for fused max-pool).
template<int CIN, int COUT, bool ACT, bool GATHER, bool WRITE, bool MAXMIN>
__global__ __launch_bounds__(256) void mm_kernel(const uint16_t* __restrict__ xin,
        const float* __restrict__ xyz, const float* __restrict__ nx,
        const uint16_t* __restrict__ ptsT, const int* __restrict__ gidx,
        const float* __restrict__ wt, const float* __restrict__ bias, const float* __restrict__ ac,
        uint16_t* __restrict__ xout, float* __restrict__ ssc,
        unsigned* __restrict__ mmax, unsigned* __restrict__ mmin){
    __shared__ __align__(16) float sw[CIN * COUT];
    __shared__ float sb[COUT];
    __shared__ float sa[ACT ? 2*CIN : 1];
    __shared__ __align__(16) float sred[16 * 260];
    const int tid = threadIdx.x;
    for (int i = tid; i < CIN * COUT; i += 256) sw[i] = wt[i];
    if (tid < COUT) sb[tid] = bias[tid];
    if constexpr (ACT){ if (tid < CIN){ sa[tid] = ac[tid]; sa[CIN + tid] = ac[128 + tid]; } }
    __syncthreads();
    const int b = blockIdx.x >> 7;
    const int ls = ((blockIdx.x & 127) << 8) + tid;
    float f[CIN];
    if constexpr (GATHER){
        const int s = ls >> 5;
        const int g = gidx[(size_t)b * LCOLS + ls];
        const float* px = xyz + (size_t)b * 3 * NPTS;
        const float cx = nx[b*3*NPOINT + s], cy = nx[b*3*NPOINT + NPOINT + s], cz = nx[b*3*NPOINT + 2*NPOINT + s];
        f[0] = sub_rn(px[g], cx); f[1] = sub_rn(px[NPTS+g], cy); f[2] = sub_rn(px[2*NPTS+g], cz);
        const u16x8* pr = (const u16x8*)(ptsT + ((size_t)b * NPTS + (size_t)g) * 64);
#pragma unroll
        for (int jj = 0; jj < 8; jj++){
            u16x8 v = pr[jj];
#pragma unroll
            for (int e = 0; e < 8; e++) f[3 + jj*8 + e] = bf2f(v[e]);
        }
    } else {
        const uint16_t* xp = xin + (size_t)b * CIN * LCOLS + ls;
#pragma unroll
        for (int c = 0; c < CIN; c++){
            float v = bf2f(xp[(size_t)c * LCOLS]);
            if constexpr (ACT) v = fmaxf(fmaf(sa[c], v, sa[CIN + c]), 0.0f);
            f[c] = v;
        }
    }
    uint16_t* op = xout + (size_t)b * COUT * LCOLS + ls;
    float* sbck = ssc + (blockIdx.x & (NBUCK-1)) * 256;
    for (int o0 = 0; o0 < COUT; o0 += 16){
        float acc[16];
#pragma unroll
        for (int j = 0; j < 16; j++) acc[j] = sb[o0 + j];
#pragma unroll
        for (int c = 0; c < CIN; c++){
            const float4* wr = (const float4*)(sw + c * COUT + o0);  // uniform -> LDS broadcast
            float4 w0_ = wr[0], w1_ = wr[1], w2_ = wr[2], w3_ = wr[3];
            const float fc = f[c];
            acc[0]  = fmaf(w0_.x, fc, acc[0]);  acc[1]  = fmaf(w0_.y, fc, acc[1]);
            acc[2]  = fmaf(w0_.z, fc, acc[2]);  acc[3]  = fmaf(w0_.w, fc, acc[3]);
            acc[4]  = fmaf(w1_.x, fc, acc[4]);  acc[5]  = fmaf(w1_.y, fc, acc[5]);
            acc[6]  = fmaf(w1_.z, fc, acc[6]);  acc[7]  = fmaf(w1_.w, fc, acc[7]);
            acc[8]  = fmaf(w2_.x, fc, acc[8]);  acc[9]  = fmaf(w2_.y, fc, acc[9]);
            acc[10] = fmaf(w2_.z, fc, acc[10]); acc[11] = fmaf(w2_.w, fc, acc[11]);
            acc[12] = fmaf(w3_.x, fc, acc[12]); acc[13] = fmaf(w3_.y, fc, acc[13]);
            acc[14] = fmaf(w3_.z, fc, acc[14]); acc[15] = fmaf(w3_.w, fc, acc[15]);
        }
        if constexpr (WRITE){
#pragma unroll
            for (int j = 0; j < 16; j++) op[(size_t)(o0 + j) * LCOLS] = f2bf(acc[j]);
        }
        // ---- block-level stats reduce on f32 accs ----
        __syncthreads();                       // protect sred reuse from previous group
#pragma unroll
        for (int k = 0; k < 16; k++) sred[k * 260 + tid] = acc[k];
        __syncthreads();
        const int ch = tid >> 4, seg = tid & 15;    // 16 ch x 16 segments of 16 cols
        float s = 0.f, ss = 0.f, mx = -1e30f, mn = 1e30f;
        const float4* rp = (const float4*)(sred + ch * 260 + seg * 16);
#pragma unroll
        for (int e = 0; e < 4; e++){
            float4 v = rp[e];
            s += v.x + v.y + v.z + v.w;
            ss = fmaf(v.x, v.x, ss); ss = fmaf(v.y, v.y, ss);
            ss = fmaf(v.z, v.z, ss); ss = fmaf(v.w, v.w, ss);
            if constexpr (MAXMIN){
                mx = fmaxf(mx, fmaxf(fmaxf(v.x, v.y), fmaxf(v.z, v.w)));
                mn = fminf(mn, fminf(fminf(v.x, v.y), fminf(v.z, v.w)));
            }
        }
        // 16 segs of one ch sit in consecutive lanes of one wave
#pragma unroll
        for (int off = 1; off < 16; off <<= 1){
            s += __shfl_xor(s, off); ss += __shfl_xor(ss, off);
            if constexpr (MAXMIN){ mx = fmaxf(mx, __shfl_xor(mx, off)); mn = fminf(mn, __shfl_xor(mn, off)); }
        }
        if (seg == 0){
            atomicAdd(&sbck[o0 + ch], s);
            atomicAdd(&sbck[128 + o0 + ch], ss);
            if constexpr (MAXMIN){
                atomicMax(&mmax[b * 128 + o0 + ch], fkey(mx));
                atomicMin(&mmin[b * 128 + o0 + ch], fkey(mn));
            }
        }
    }
}

// ---------- 6) BN params from bucketed sums -> per-channel affine a,c ----------
__global__ void params_kernel(const float* __restrict__ ssc, const float* __restrict__ g,
                              const float* __restrict__ beta, float* __restrict__ ac, int C){
    int o = threadIdx.x;
    if (o < C){
        float s = 0.f, ss = 0.f;
        for (int k = 0; k < NBUCK; k++){ s += ssc[k*256 + o]; ss += ssc[k*256 + 128 + o]; }
        const float inv = 1.0f / NTOT;
        float mean = s * inv;
        float var  = ss * inv - mean * mean;
        float a = g[o] / sqrtf(var + 1e-5f);
        ac[o] = a;
        ac[128 + o] = fmaf(-mean, a, beta[o]);
    }
}

// ---------- 7) finalize: out = relu(a * (a>=0 ? max : min) + c) per (b,ch) ----------
__global__ __launch_bounds__(64) void final_kernel(const float* __restrict__ ssc, const float* __restrict__ g2,
                                                   const float* __restrict__ be2, const unsigned* __restrict__ mmax,
                                                   const unsigned* __restrict__ mmin, float* __restrict__ out){
    const int t = blockIdx.x * 64 + threadIdx.x;   // 0..2047 : b*128+o
    const int o = t & 127;
    float s = 0.f, ss = 0.f;
    for (int k = 0; k < NBUCK; k++){ s += ssc[k*256 + o]; ss += ssc[k*256 + 128 + o]; }
    const float inv = 1.0f / NTOT;
    float mean = s * inv;
    float var  = ss * inv - mean * mean;
    float a = g2[o] / sqrtf(var + 1e-5f);
    float c = fmaf(-mean, a, be2[o]);
    unsigned k = (a >= 0.f) ? mmax[t] : mmin[t];   // relu(a*x+c) monotone in x, direction sign(a)
    float x = funkey(k);
    out[49152 + t] = fmaxf(fmaf(a, x, c), 0.0f);
}

extern "C" void kernel_launch(void* const* d_in, const int* in_sizes, int n_in,
                              void* d_out, int out_size, void* d_ws, size_t ws_size,
                              hipStream_t stream){
    const float* xyz = (const float*)d_in[0];
    const float* pts = (const float*)d_in[1];
    const float* w0  = (const float*)d_in[2];  const float* b0  = (const float*)d_in[3];
    const float* g0  = (const float*)d_in[4];  const float* be0 = (const float*)d_in[5];
    const float* w1  = (const float*)d_in[6];  const float* b1  = (const float*)d_in[7];
    const float* g1  = (const float*)d_in[8];  const float* be1 = (const float*)d_in[9];
    const float* w2  = (const float*)d_in[10]; const float* b2  = (const float*)d_in[11];
    const float* g2  = (const float*)d_in[12]; const float* be2 = (const float*)d_in[13];
    float* out = (float*)d_out;
    char* ws = (char*)d_ws;

    int*      fps_idx = (int*)(ws + OFF_FPS);
    int*      gidx    = (int*)(ws + OFF_GIDX);
    float*    ssc0    = (float*)(ws + OFF_SSC);            // 32*256
    float*    ssc1    = ssc0 + NBUCK*256;
    float*    ssc2    = ssc1 + NBUCK*256;
    float*    par0    = (float*)(ws + OFF_PAR);
    float*    par1    = par0 + 256;
    unsigned* mmax    = (unsigned*)(ws + OFF_MM);
    unsigned* mmin    = mmax + 2048;
    float*    wt0     = (float*)(ws + OFF_WT);
    float*    wt1     = wt0 + 67*64;
    float*    wt2     = wt1 + 64*64;
    uint16_t* t0      = (uint16_t*)(ws + OFF_T0);
    uint16_t* t1      = (uint16_t*)(ws + OFF_T1);
    uint16_t* ptsT    = (uint16_t*)(ws + OFF_PTST);

    hipMemsetAsync(ws + OFF_SSC, 0, 3 * NBUCK * 256 * 4, stream);
    hipMemsetAsync(ws + OFF_MM, 0x00, 8192, stream);          // key 0 < key(-inf)
    hipMemsetAsync(ws + OFF_MM + 8192, 0xFF, 8192, stream);   // key ~0 > key(+inf)

    prep_kernel<<<32, 256, 0, stream>>>(w0, w1, w2, wt0, wt1, wt2);
    fps_kernel<<<NBATCH, 1024, 0, stream>>>(xyz, fps_idx, out);
    transpose_kernel<<<2048, 256, 0, stream>>>(pts, ptsT);
    ballquery_kernel<<<4096, 256, 0, stream>>>(xyz, fps_idx, gidx);

    mm_kernel<67, 64, false, true, true, false><<<2048, 256, 0, stream>>>(
        nullptr, xyz, out, ptsT, gidx, wt0, b0, nullptr, t0, ssc0, nullptr, nullptr);
    params_kernel<<<1, 128, 0, stream>>>(ssc0, g0, be0, par0, 64);

    mm_kernel<64, 64, true, false, true, false><<<2048, 256, 0, stream>>>(
        t0, nullptr, nullptr, nullptr, nullptr, wt1, b1, par0, t1, ssc1, nullptr, nullptr);
    params_kernel<<<1, 128, 0, stream>>>(ssc1, g1, be1, par1, 64);

    mm_kernel<64, 128, true, false, false, true><<<2048, 256, 0, stream>>>(
        t1, nullptr, nullptr, nullptr, nullptr, wt2, b2, par1, nullptr, ssc2, mmax, mmin);
    final_kernel<<<32, 64, 0, stream>>>(ssc2, g2, be2, mmax, mmin, out);
}